// Round 1
// baseline (377.056 us; speedup 1.0000x reference)
//
#include <hip/hip_runtime.h>
#include <hip/hip_bf16.h>
#include <cstdint>
#include <cstddef>

#define BB 2
#define NN 2048
#define DD 1024
#define HH 16
#define DKK 64
#define SCALE 0.125f
#define LOG2E 1.4426950408889634f

typedef __bf16 bf16;
typedef __bf16 bf16x4 __attribute__((ext_vector_type(4)));
typedef __bf16 bf16x8 __attribute__((ext_vector_type(8)));
typedef float f32x4 __attribute__((ext_vector_type(4)));

// async global->LDS, 16B per lane. dst must be wave-uniform-base + lane*16
// (we pass the per-lane address that satisfies exactly that mapping).
#define GLD(gp, lp)                                                            \
  __builtin_amdgcn_global_load_lds(                                            \
      (const __attribute__((address_space(1))) void*)(gp),                     \
      (__attribute__((address_space(3))) void*)(lp), 16, 0, 0)

// ---------------- fp32 -> bf16 convert ----------------
__global__ void k_cvt(const float* __restrict__ s, bf16* __restrict__ d, int n) {
  int i = (blockIdx.x * 256 + threadIdx.x) * 4;
  if (i >= n) return;
  float4 f = *(const float4*)(s + i);
  bf16x4 o;
  o.x = (bf16)f.x; o.y = (bf16)f.y; o.z = (bf16)f.z; o.w = (bf16)f.w;
  *(bf16x4*)(d + i) = o;
}

// ---------------- GEMM: out = A @ W^T + bias ----------------
// A: [M][K] bf16 row-major (M=4096, K=1024)
// W: [Nout][K] bf16 row-major (Nout=1024)  (i.e. B^T layout)
// mode 0: write bf16 to outB at [b][h][row][dk]   (Q/K projection)
// mode 2: write bf16 to outB at [b][h][dk][row]   (V projection, transposed)
// mode 3: write fp32 to outF row-major [M][Nout]  (output projection)
__global__ __launch_bounds__(256, 2) void k_gemm(
    const bf16* __restrict__ A, const bf16* __restrict__ W,
    const float* __restrict__ bias, bf16* __restrict__ outB,
    float* __restrict__ outF, int mode) {
  const int K = 1024;
  __shared__ bf16 lA[128 * 32];
  __shared__ bf16 lB[128 * 32];
  const int t = threadIdx.x;
  const int lane = t & 63;
  const int quad = lane >> 4;
  const int l16 = lane & 15;
  const int w = t >> 6;
  const int wm = (w >> 1) * 64;
  const int wn = (w & 1) * 64;
  const int m0 = blockIdx.y * 128;
  const int n0 = blockIdx.x * 128;

  f32x4 acc[4][4] = {};

  // staging map: thread t, inst i covers tile bytes [t*16 + i*4096, +16)
  const int srow = t >> 2;         // tile row (of 64 per inst)
  const int scol = (t & 3) * 8;    // k-elem offset
  const bf16* ga = A + (size_t)(m0 + srow) * K + scol;
  const bf16* gb = W + (size_t)(n0 + srow) * K + scol;

  for (int kb = 0; kb < K; kb += 32) {
    __syncthreads();  // previous iter's LDS reads done
    GLD(ga + kb,            lA + t * 8);
    GLD(ga + kb + 64 * K,   lA + t * 8 + 2048);
    GLD(gb + kb,            lB + t * 8);
    GLD(gb + kb + 64 * K,   lB + t * 8 + 2048);
    __syncthreads();  // staging complete (drains vmcnt)

    bf16x8 af[4], bf[4];
#pragma unroll
    for (int i = 0; i < 4; i++) {
      af[i] = *(const bf16x8*)(lA + (wm + i * 16 + l16) * 32 + quad * 8);
      bf[i] = *(const bf16x8*)(lB + (wn + i * 16 + l16) * 32 + quad * 8);
    }
#pragma unroll
    for (int mi = 0; mi < 4; mi++)
#pragma unroll
      for (int ni = 0; ni < 4; ni++)
        acc[mi][ni] = __builtin_amdgcn_mfma_f32_16x16x32_bf16(
            af[mi], bf[ni], acc[mi][ni], 0, 0, 0);
  }

  // epilogue: C/D layout col=lane&15, row=quad*4+reg (m89-verified)
#pragma unroll
  for (int mi = 0; mi < 4; mi++) {
#pragma unroll
    for (int ni = 0; ni < 4; ni++) {
#pragma unroll
      for (int r = 0; r < 4; r++) {
        int gm = m0 + wm + mi * 16 + quad * 4 + r;
        int gn = n0 + wn + ni * 16 + l16;
        float v = acc[mi][ni][r] + bias[gn];
        if (mode == 3) {
          outF[(size_t)gm * 1024 + gn] = v;
        } else {
          int b = gm >> 11, row = gm & 2047;
          int h = gn >> 6, dk = gn & 63;
          if (mode == 2)
            outB[((size_t)(b * HH + h) * DKK + dk) * NN + row] = (bf16)v;
          else
            outB[((size_t)(b * HH + h) * NN + row) * DKK + dk] = (bf16)v;
        }
      }
    }
  }
}

// ---------------- flash attention ----------------
// Qp,Kp: [B][H][N][DK] bf16 ; Vt: [B][H][DK][N] bf16 ; Ao: [B][N][H*DK] bf16
__global__ __launch_bounds__(256, 2) void k_attn(
    const bf16* __restrict__ Qp, const bf16* __restrict__ Kp,
    const bf16* __restrict__ Vt, bf16* __restrict__ Ao) {
  __shared__ bf16 lK[128 * 64];        // [key][dk]   16KB
  __shared__ bf16 lV[64 * 128];        // [dk][key]   16KB
  __shared__ bf16 lP[4 * 32 * 128];    // per-wave P  32KB
  const int t = threadIdx.x;
  const int lane = t & 63;
  const int quad = lane >> 4;
  const int l16 = lane & 15;
  const int w = t >> 6;
  const int bh = blockIdx.y;
  const int qt = blockIdx.x;
  const bf16* Qb = Qp + (size_t)bh * NN * DKK;
  const bf16* Kb = Kp + (size_t)bh * NN * DKK;
  const bf16* Vb = Vt + (size_t)bh * DKK * NN;

  // Q fragments (A-layout: m=lane&15, k=quad*8+j), rows qr0..qr0+31 per wave
  const int qr0 = qt * 128 + w * 32;
  bf16x8 qf[2][2];
#pragma unroll
  for (int mi = 0; mi < 2; mi++)
#pragma unroll
    for (int kq = 0; kq < 2; kq++)
      qf[mi][kq] = *(const bf16x8*)(Qb + (size_t)(qr0 + mi * 16 + l16) * DKK +
                                    kq * 32 + quad * 8);

  float mst[2][4], lst[2][4];
  f32x4 oacc[2][4] = {};
#pragma unroll
  for (int mi = 0; mi < 2; mi++)
#pragma unroll
    for (int r = 0; r < 4; r++) { mst[mi][r] = -3.0e38f; lst[mi][r] = 0.f; }

  const float c = SCALE * LOG2E;

  for (int kt = 0; kt < NN; kt += 128) {
    __syncthreads();  // previous iter's lV/lK reads done
    // stage K tile [128][64] and V tile [64][128] (16KB each, 4 insts each)
#pragma unroll
    for (int i = 0; i < 4; i++) {
      int o = t * 16 + i * 4096;            // byte offset in tile
      int krow = o >> 7, kcol = (o & 127) >> 1;
      GLD(Kb + (size_t)(kt + krow) * DKK + kcol, lK + (o >> 1));
      int vrow = o >> 8, vcol = (o & 255) >> 1;
      GLD(Vb + (size_t)vrow * NN + kt + vcol, lV + (o >> 1));
    }
    __syncthreads();  // staging complete

    // S = Q K^T  (C-layout result)
    f32x4 s[2][8];
#pragma unroll
    for (int ni = 0; ni < 8; ni++) {
      bf16x8 kf0 = *(const bf16x8*)(lK + (ni * 16 + l16) * 64 + quad * 8);
      bf16x8 kf1 = *(const bf16x8*)(lK + (ni * 16 + l16) * 64 + 32 + quad * 8);
#pragma unroll
      for (int mi = 0; mi < 2; mi++) {
        f32x4 z = {0.f, 0.f, 0.f, 0.f};
        z = __builtin_amdgcn_mfma_f32_16x16x32_bf16(qf[mi][0], kf0, z, 0, 0, 0);
        z = __builtin_amdgcn_mfma_f32_16x16x32_bf16(qf[mi][1], kf1, z, 0, 0, 0);
        s[mi][ni] = z;
      }
    }

    // online softmax; rows live inside a 16-lane quad
#pragma unroll
    for (int mi = 0; mi < 2; mi++) {
      float alpha[4];
#pragma unroll
      for (int r = 0; r < 4; r++) {
        float mx = s[mi][0][r];
#pragma unroll
        for (int ni = 1; ni < 8; ni++) mx = fmaxf(mx, s[mi][ni][r]);
#pragma unroll
        for (int dd = 1; dd < 16; dd <<= 1) mx = fmaxf(mx, __shfl_xor(mx, dd));
        float mn = fmaxf(mst[mi][r], mx);
        alpha[r] = exp2f((mst[mi][r] - mn) * c);
        mst[mi][r] = mn;
      }
      float rs[4] = {0.f, 0.f, 0.f, 0.f};
#pragma unroll
      for (int ni = 0; ni < 8; ni++)
#pragma unroll
        for (int r = 0; r < 4; r++) {
          float p = exp2f((s[mi][ni][r] - mst[mi][r]) * c);
          s[mi][ni][r] = p;
          rs[r] += p;
        }
#pragma unroll
      for (int r = 0; r < 4; r++) {
#pragma unroll
        for (int dd = 1; dd < 16; dd <<= 1) rs[r] += __shfl_xor(rs[r], dd);
        lst[mi][r] = lst[mi][r] * alpha[r] + rs[r];
      }
#pragma unroll
      for (int ni = 0; ni < 4; ni++)
#pragma unroll
        for (int r = 0; r < 4; r++) oacc[mi][ni][r] *= alpha[r];
      // P: C-layout -> LDS (per-wave region), later re-read in A-layout
#pragma unroll
      for (int ni = 0; ni < 8; ni++)
#pragma unroll
        for (int r = 0; r < 4; r++)
          lP[w * 4096 + (mi * 16 + quad * 4 + r) * 128 + ni * 16 + l16] =
              (bf16)s[mi][ni][r];
    }

    // O += P V   (A from lP in A-layout, B from lV [dk-major])
#pragma unroll
    for (int kq = 0; kq < 4; kq++) {
      bf16x8 pa[2];
#pragma unroll
      for (int mi = 0; mi < 2; mi++)
        pa[mi] = *(const bf16x8*)(lP + w * 4096 + (mi * 16 + l16) * 128 +
                                  kq * 32 + quad * 8);
#pragma unroll
      for (int ni = 0; ni < 4; ni++) {
        bf16x8 vb =
            *(const bf16x8*)(lV + (ni * 16 + l16) * 128 + kq * 32 + quad * 8);
#pragma unroll
        for (int mi = 0; mi < 2; mi++)
          oacc[mi][ni] = __builtin_amdgcn_mfma_f32_16x16x32_bf16(
              pa[mi], vb, oacc[mi][ni], 0, 0, 0);
      }
    }
  }

  // epilogue: O /= l, write Ao[b][row][h*64+dk]
  const int b = bh >> 4, h = bh & 15;
#pragma unroll
  for (int mi = 0; mi < 2; mi++)
#pragma unroll
    for (int ni = 0; ni < 4; ni++)
#pragma unroll
      for (int r = 0; r < 4; r++) {
        int row = qr0 + mi * 16 + quad * 4 + r;
        float v = oacc[mi][ni][r] / lst[mi][r];
        Ao[(size_t)(b * NN + row) * DD + h * DKK + ni * 16 + l16] = (bf16)v;
      }
}

extern "C" void kernel_launch(void* const* d_in, const int* in_sizes, int n_in,
                              void* d_out, int out_size, void* d_ws,
                              size_t ws_size, hipStream_t stream) {
  const float* qin = (const float*)d_in[0];
  const float* kin = (const float*)d_in[1];
  const float* vin = (const float*)d_in[2];
  const float* Wq = (const float*)d_in[3];
  const float* bq = (const float*)d_in[4];
  const float* Wk = (const float*)d_in[5];
  const float* bk = (const float*)d_in[6];
  const float* Wv = (const float*)d_in[7];
  const float* bv = (const float*)d_in[8];
  const float* Wo = (const float*)d_in[9];
  const float* bo = (const float*)d_in[10];
  float* out = (float*)d_out;

  const int MN = BB * NN * DD;  // 4M elems
  const int WNel = DD * DD;     // 1M elems
  bf16* ws = (bf16*)d_ws;
  bf16* xb = ws;                 // 4M (reused: q, then k, then v, then Ao)
  bf16* wqb = xb + MN;           // 1M
  bf16* wkb = wqb + WNel;
  bf16* wvb = wkb + WNel;
  bf16* wob = wvb + WNel;
  bf16* Qp = wob + WNel;         // 4M
  bf16* Kp = Qp + MN;            // 4M
  bf16* Vt = Kp + MN;            // 4M  -> total 20M elems = 40MB

  dim3 cg(MN / 1024), cw(WNel / 1024);
  dim3 gg(8, 32), ag(16, 32);

  k_cvt<<<cw, 256, 0, stream>>>(Wq, wqb, WNel);
  k_cvt<<<cw, 256, 0, stream>>>(Wk, wkb, WNel);
  k_cvt<<<cw, 256, 0, stream>>>(Wv, wvb, WNel);
  k_cvt<<<cw, 256, 0, stream>>>(Wo, wob, WNel);

  k_cvt<<<cg, 256, 0, stream>>>(qin, xb, MN);
  k_gemm<<<gg, 256, 0, stream>>>(xb, wqb, bq, Qp, nullptr, 0);
  k_cvt<<<cg, 256, 0, stream>>>(kin, xb, MN);
  k_gemm<<<gg, 256, 0, stream>>>(xb, wkb, bk, Kp, nullptr, 0);
  k_cvt<<<cg, 256, 0, stream>>>(vin, xb, MN);
  k_gemm<<<gg, 256, 0, stream>>>(xb, wvb, bv, Vt, nullptr, 2);

  k_attn<<<ag, 256, 0, stream>>>(Qp, Kp, Vt, xb);
  k_gemm<<<gg, 256, 0, stream>>>(xb, wob, bo, nullptr, out, 3);
}

// Round 2
// 252.901 us; speedup vs baseline: 1.4909x; 1.4909x over previous
//
#include <hip/hip_runtime.h>
#include <hip/hip_bf16.h>
#include <cstdint>
#include <cstddef>

#define BB 2
#define NN 2048
#define DD 1024
#define HH 16
#define DKK 64
#define SCALE 0.125f
#define LOG2E 1.4426950408889634f

typedef __bf16 bf16;
typedef __bf16 bf16x4 __attribute__((ext_vector_type(4)));
typedef __bf16 bf16x8 __attribute__((ext_vector_type(8)));
typedef float f32x4 __attribute__((ext_vector_type(4)));
typedef short s16x4 __attribute__((ext_vector_type(4)));

// async global->LDS, 16B/lane; LDS dst = wave-uniform base + lane*16.
#define GLD(gp, lp)                                                            \
  __builtin_amdgcn_global_load_lds(                                            \
      (const __attribute__((address_space(1))) void*)(gp),                     \
      (__attribute__((address_space(3))) void*)(lp), 16, 0, 0)

// ---------------- fp32 -> bf16 convert (multi-buffer via grid.y) -----------
struct CvtArgs { const float* s[4]; bf16* d[4]; };

__global__ void k_cvtN(CvtArgs a, int n) {
  const float* __restrict__ s = a.s[blockIdx.y];
  bf16* __restrict__ d = a.d[blockIdx.y];
  int i = (blockIdx.x * 256 + threadIdx.x) * 4;
  if (i >= n) return;
  float4 f = *(const float4*)(s + i);
  bf16x4 o;
  o.x = (bf16)f.x; o.y = (bf16)f.y; o.z = (bf16)f.z; o.w = (bf16)f.w;
  *(bf16x4*)(d + i) = o;
}

// ---------------- GEMM body: out = A @ W^T + bias --------------------------
// A:[M=4096][K=1024] bf16, W:[1024][K] bf16.
// mode 0: bf16 out [b][h][row][dk]; mode 2: bf16 out [b][h][dk][row];
// mode 3: fp32 out row-major.
// LDS tiles are XOR-chunk-swizzled (4 chunks/row of 16B): chunk c of row r
// lives at chunk c^(r&3)  -> fragment reads spread banks (8-way -> 4-way).
__device__ __forceinline__ void gemm_body(
    const bf16* __restrict__ A, const bf16* __restrict__ W,
    const float* __restrict__ bias, bf16* __restrict__ outB,
    float* __restrict__ outF, int mode, int m0, int n0) {
  const int K = 1024;
  __shared__ bf16 lA[128 * 32];
  __shared__ bf16 lB[128 * 32];
  const int t = threadIdx.x;
  const int lane = t & 63;
  const int quad = lane >> 4;
  const int l16 = lane & 15;
  const int w = t >> 6;
  const int wm = (w >> 1) * 64;
  const int wn = (w & 1) * 64;

  f32x4 acc[4][4] = {};

  // staging: LDS chunk index i=inst*256+t  ->  row r=i>>2, swizzled col
  int i0 = t, i1 = t + 256;
  int r0 = i0 >> 2, c0 = (i0 & 3) ^ (r0 & 3);
  int r1 = i1 >> 2, c1 = (i1 & 3) ^ (r1 & 3);
  const bf16* gA0 = A + (size_t)(m0 + r0) * K + c0 * 8;
  const bf16* gA1 = A + (size_t)(m0 + r1) * K + c1 * 8;
  const bf16* gB0 = W + (size_t)(n0 + r0) * K + c0 * 8;
  const bf16* gB1 = W + (size_t)(n0 + r1) * K + c1 * 8;

  const int swzA = (quad ^ (l16 & 3)) * 8;  // fragment-read chunk offset

  for (int kb = 0; kb < K; kb += 32) {
    __syncthreads();
    GLD(gA0 + kb, lA + i0 * 8);
    GLD(gA1 + kb, lA + i1 * 8);
    GLD(gB0 + kb, lB + i0 * 8);
    GLD(gB1 + kb, lB + i1 * 8);
    __syncthreads();

    bf16x8 af[4], bf[4];
#pragma unroll
    for (int i = 0; i < 4; i++) {
      af[i] = *(const bf16x8*)(lA + (wm + i * 16 + l16) * 32 + swzA);
      bf[i] = *(const bf16x8*)(lB + (wn + i * 16 + l16) * 32 + swzA);
    }
#pragma unroll
    for (int mi = 0; mi < 4; mi++)
#pragma unroll
      for (int ni = 0; ni < 4; ni++)
        acc[mi][ni] = __builtin_amdgcn_mfma_f32_16x16x32_bf16(
            af[mi], bf[ni], acc[mi][ni], 0, 0, 0);
  }

  // C/D layout: col=lane&15, row=quad*4+reg (m89-verified)
#pragma unroll
  for (int mi = 0; mi < 4; mi++) {
#pragma unroll
    for (int ni = 0; ni < 4; ni++) {
#pragma unroll
      for (int r = 0; r < 4; r++) {
        int gm = m0 + wm + mi * 16 + quad * 4 + r;
        int gn = n0 + wn + ni * 16 + l16;
        float v = acc[mi][ni][r] + bias[gn];
        if (mode == 3) {
          outF[(size_t)gm * 1024 + gn] = v;
        } else {
          int b = gm >> 11, row = gm & 2047;
          int h = gn >> 6, dk = gn & 63;
          if (mode == 2)
            outB[((size_t)(b * HH + h) * DKK + dk) * NN + row] = (bf16)v;
          else
            outB[((size_t)(b * HH + h) * NN + row) * DKK + dk] = (bf16)v;
        }
      }
    }
  }
}

__global__ __launch_bounds__(256, 2) void k_gemm(
    const bf16* __restrict__ A, const bf16* __restrict__ W,
    const float* __restrict__ bias, bf16* __restrict__ outB,
    float* __restrict__ outF, int mode) {
  gemm_body(A, W, bias, outB, outF, mode, blockIdx.y * 128, blockIdx.x * 128);
}

struct GemmArgs { const bf16* A[3]; const bf16* W[3]; const float* b[3]; bf16* o[3]; };

__global__ __launch_bounds__(256, 2) void k_gemm3(GemmArgs g) {
  int z = blockIdx.z;
  gemm_body(g.A[z], g.W[z], g.b[z], g.o[z], nullptr, z == 2 ? 2 : 0,
            blockIdx.y * 128, blockIdx.x * 128);
}

// ---------------- flash attention (S^T trick, no P round-trip) -------------
// Qp,Kp: [B][H][N][DK] bf16 ; Vt: [B][H][DK][N] bf16 ; Ao: [B][N][H*DK] bf16
// S^T = K*Q^T comes out in C-layout (col=qrow=lane&15, row=key=quad*4+r),
// which IS the A-frag layout of mfma_f32_16x16x16bf16_1k (m=lane&15,
// k=quad*4+j) -> P goes straight from registers into PV.
// lK [128 keys][64 dk] swizzled by 16B chunk: c' = c ^ (r&7)  (8 chunks/row)
// lV [64 dk][128 keys] swizzled:              c' = c ^ (r&15) (16 chunks/row)
__global__ __launch_bounds__(256, 2) void k_attn(
    const bf16* __restrict__ Qp, const bf16* __restrict__ Kp,
    const bf16* __restrict__ Vt, bf16* __restrict__ Ao) {
  __shared__ bf16 lK[128 * 64];  // 16KB
  __shared__ bf16 lV[64 * 128];  // 16KB
  const int t = threadIdx.x;
  const int lane = t & 63;
  const int quad = lane >> 4;
  const int l16 = lane & 15;
  const int w = t >> 6;
  const int bh = blockIdx.y;
  const int qt = blockIdx.x;
  const bf16* Qb = Qp + (size_t)bh * NN * DKK;
  const bf16* Kb = Kp + (size_t)bh * NN * DKK;
  const bf16* Vb = Vt + (size_t)bh * DKK * NN;

  // Q B-frags (n=qrow=lane&15, k=dk=quad*8+j) straight from global
  const int qr0 = qt * 128 + w * 32;
  bf16x8 qf[2][2];
#pragma unroll
  for (int j = 0; j < 2; j++)
#pragma unroll
    for (int kq = 0; kq < 2; kq++)
      qf[j][kq] = *(const bf16x8*)(Qb + (size_t)(qr0 + j * 16 + l16) * DKK +
                                   kq * 32 + quad * 8);

  float mj[2] = {-3.0e38f, -3.0e38f}, lj[2] = {0.f, 0.f};
  f32x4 oacc[2][4] = {};
  const float c = SCALE * LOG2E;

  // precompute swizzled staging pointers (4 insts each for K and V)
  const bf16* gK[4]; const bf16* gV[4];
#pragma unroll
  for (int i4 = 0; i4 < 4; i4++) {
    int i = i4 * 256 + t;
    int rK = i >> 3, cK = (i & 7) ^ (rK & 7);
    gK[i4] = Kb + (size_t)rK * DKK + cK * 8;
    int rV = i >> 4, cV = (i & 15) ^ (rV & 15);
    gV[i4] = Vb + (size_t)rV * NN + cV * 8;
  }
  const int swzK0 = ((quad) ^ (l16 & 7)) * 8;      // kf0 chunk offset
  const int swzK1 = ((4 + quad) ^ (l16 & 7)) * 8;  // kf1 chunk offset

  for (int kt = 0; kt < NN; kt += 128) {
    __syncthreads();
#pragma unroll
    for (int i4 = 0; i4 < 4; i4++) {
      GLD(gK[i4] + (size_t)kt * DKK, lK + (i4 * 256 + t) * 8);
      GLD(gV[i4] + kt, lV + (i4 * 256 + t) * 8);
    }
    __syncthreads();

    // S^T = K Q^T : A = K-frag (m=key), B = Q-frag (n=qrow)
    f32x4 s[2][8];
#pragma unroll
    for (int tt = 0; tt < 8; tt++) {
      const bf16* kbase = lK + (tt * 16 + l16) * 64;
      bf16x8 kf0 = *(const bf16x8*)(kbase + swzK0);
      bf16x8 kf1 = *(const bf16x8*)(kbase + swzK1);
#pragma unroll
      for (int j = 0; j < 2; j++) {
        f32x4 z = {0.f, 0.f, 0.f, 0.f};
        z = __builtin_amdgcn_mfma_f32_16x16x32_bf16(kf0, qf[j][0], z, 0, 0, 0);
        z = __builtin_amdgcn_mfma_f32_16x16x32_bf16(kf1, qf[j][1], z, 0, 0, 0);
        s[j][tt] = z;
      }
    }

    // online softmax; lane's qrow = j*16+l16, keys = kt+tt*16+quad*4+r
    s16x4 pa[2][8];
#pragma unroll
    for (int j = 0; j < 2; j++) {
      float mx = -3.0e38f;
#pragma unroll
      for (int tt = 0; tt < 8; tt++)
#pragma unroll
        for (int r = 0; r < 4; r++) mx = fmaxf(mx, s[j][tt][r]);
      mx = fmaxf(mx, __shfl_xor(mx, 16));
      mx = fmaxf(mx, __shfl_xor(mx, 32));
      float mn = fmaxf(mj[j], mx);
      float al = __builtin_amdgcn_exp2f((mj[j] - mn) * c);
      mj[j] = mn;
      float rs = 0.f;
#pragma unroll
      for (int tt = 0; tt < 8; tt++) {
        bf16x4 pb;
#pragma unroll
        for (int r = 0; r < 4; r++) {
          float p = __builtin_amdgcn_exp2f((s[j][tt][r] - mn) * c);
          rs += p;
          pb[r] = (bf16)p;
        }
        pa[j][tt] = __builtin_bit_cast(s16x4, pb);
      }
      rs += __shfl_xor(rs, 16);
      rs += __shfl_xor(rs, 32);
      lj[j] = lj[j] * al + rs;
      // rescale O (O rows = quad*4+r): fetch alpha for those rows
      float alr[4];
#pragma unroll
      for (int r = 0; r < 4; r++) alr[r] = __shfl(al, quad * 4 + r);
#pragma unroll
      for (int ni = 0; ni < 4; ni++)
#pragma unroll
        for (int r = 0; r < 4; r++) oacc[j][ni][r] *= alr[r];
    }

    // O += P V : A = P-frag (regs), B = V-frag from lV (k=key, n=dk)
#pragma unroll
    for (int tt = 0; tt < 8; tt++) {
#pragma unroll
      for (int ni = 0; ni < 4; ni++) {
        int rv = ni * 16 + l16;
        int cc = 2 * tt + (quad >> 1);
        const bf16* vaddr =
            lV + rv * 128 + ((cc ^ l16) * 8) + (quad & 1) * 4;
        s16x4 vb = __builtin_bit_cast(s16x4, *(const bf16x4*)vaddr);
#pragma unroll
        for (int j = 0; j < 2; j++)
          oacc[j][ni] = __builtin_amdgcn_mfma_f32_16x16x16bf16_1k(
              pa[j][tt], vb, oacc[j][ni], 0, 0, 0);
      }
    }
  }

  // epilogue: rows = qr0 + j*16 + quad*4 + r, cols dk = ni*16+l16
  const int b = bh >> 4, h = bh & 15;
#pragma unroll
  for (int j = 0; j < 2; j++) {
    float inv[4];
#pragma unroll
    for (int r = 0; r < 4; r++) inv[r] = 1.0f / __shfl(lj[j], quad * 4 + r);
#pragma unroll
    for (int ni = 0; ni < 4; ni++)
#pragma unroll
      for (int r = 0; r < 4; r++) {
        int row = qr0 + j * 16 + quad * 4 + r;
        Ao[(size_t)(b * NN + row) * DD + h * DKK + ni * 16 + l16] =
            (bf16)(oacc[j][ni][r] * inv[r]);
      }
  }
}

extern "C" void kernel_launch(void* const* d_in, const int* in_sizes, int n_in,
                              void* d_out, int out_size, void* d_ws,
                              size_t ws_size, hipStream_t stream) {
  const float* qin = (const float*)d_in[0];
  const float* kin = (const float*)d_in[1];
  const float* vin = (const float*)d_in[2];
  const float* Wq = (const float*)d_in[3];
  const float* bq = (const float*)d_in[4];
  const float* Wk = (const float*)d_in[5];
  const float* bk = (const float*)d_in[6];
  const float* Wv = (const float*)d_in[7];
  const float* bv = (const float*)d_in[8];
  const float* Wo = (const float*)d_in[9];
  const float* bo = (const float*)d_in[10];
  float* out = (float*)d_out;

  const int MN = BB * NN * DD;  // 4M elems
  const int WNel = DD * DD;     // 1M elems
  bf16* ws = (bf16*)d_ws;

  if (ws_size >= (size_t)(3 * MN + 4 * WNel + 3 * MN) * sizeof(bf16)) {
    // fused path: 56MB — independent q/k/v buffers, one z=3 QKV dispatch
    bf16* xq = ws;
    bf16* xk = xq + MN;
    bf16* xv = xk + MN;
    bf16* wqb = xv + MN;
    bf16* wkb = wqb + WNel;
    bf16* wvb = wkb + WNel;
    bf16* wob = wvb + WNel;
    bf16* Qp = wob + WNel;
    bf16* Kp = Qp + MN;
    bf16* Vt = Kp + MN;
    bf16* Ao = xq;  // reuse

    CvtArgs ci{{qin, kin, vin, nullptr}, {xq, xk, xv, nullptr}};
    k_cvtN<<<dim3(MN / 1024, 3), 256, 0, stream>>>(ci, MN);
    CvtArgs cw{{Wq, Wk, Wv, Wo}, {wqb, wkb, wvb, wob}};
    k_cvtN<<<dim3(WNel / 1024, 4), 256, 0, stream>>>(cw, WNel);

    GemmArgs g{{xq, xk, xv}, {wqb, wkb, wvb}, {bq, bk, bv}, {Qp, Kp, Vt}};
    k_gemm3<<<dim3(8, 32, 3), 256, 0, stream>>>(g);

    k_attn<<<dim3(16, 32), 256, 0, stream>>>(Qp, Kp, Vt, Ao);
    k_gemm<<<dim3(8, 32), 256, 0, stream>>>(Ao, wob, bo, nullptr, out, 3);
  } else {
    // fallback: 40MB sequential (round-0 layout)
    bf16* xb = ws;
    bf16* wqb = xb + MN;
    bf16* wkb = wqb + WNel;
    bf16* wvb = wkb + WNel;
    bf16* wob = wvb + WNel;
    bf16* Qp = wob + WNel;
    bf16* Kp = Qp + MN;
    bf16* Vt = Kp + MN;

    CvtArgs cw{{Wq, Wk, Wv, Wo}, {wqb, wkb, wvb, wob}};
    k_cvtN<<<dim3(WNel / 1024, 4), 256, 0, stream>>>(cw, WNel);

    CvtArgs c0{{qin, nullptr, nullptr, nullptr}, {xb, nullptr, nullptr, nullptr}};
    k_cvtN<<<dim3(MN / 1024, 1), 256, 0, stream>>>(c0, MN);
    k_gemm<<<dim3(8, 32), 256, 0, stream>>>(xb, wqb, bq, Qp, nullptr, 0);
    CvtArgs c1{{kin, nullptr, nullptr, nullptr}, {xb, nullptr, nullptr, nullptr}};
    k_cvtN<<<dim3(MN / 1024, 1), 256, 0, stream>>>(c1, MN);
    k_gemm<<<dim3(8, 32), 256, 0, stream>>>(xb, wkb, bk, Kp, nullptr, 0);
    CvtArgs c2{{vin, nullptr, nullptr, nullptr}, {xb, nullptr, nullptr, nullptr}};
    k_cvtN<<<dim3(MN / 1024, 1), 256, 0, stream>>>(c2, MN);
    k_gemm<<<dim3(8, 32), 256, 0, stream>>>(xb, wvb, bv, Vt, nullptr, 2);

    k_attn<<<dim3(16, 32), 256, 0, stream>>>(Qp, Kp, Vt, xb);
    k_gemm<<<dim3(8, 32), 256, 0, stream>>>(xb, wob, bo, nullptr, out, 3);
  }
}